// Round 7
// baseline (360.816 us; speedup 1.0000x reference)
//
#include <hip/hip_runtime.h>
#include <hip/hip_bf16.h>

typedef __bf16 bf16x8 __attribute__((ext_vector_type(8)));
typedef float  f32x4  __attribute__((ext_vector_type(4)));

#define GRID2 256
// d_out offsets (floats)
#define O_FINAL 0
#define O_H     512
#define O_C     1049088      // 512 + 4*256*1024
#define O_NORM  2097664      // O_C + 4*256*1024

__device__ __forceinline__ void gridbar(int* slot) {
  __syncthreads();
  if (threadIdx.x == 0) {
    __hip_atomic_fetch_add(slot, 1, __ATOMIC_ACQ_REL, __HIP_MEMORY_SCOPE_AGENT);
    while (__hip_atomic_load(slot, __ATOMIC_RELAXED, __HIP_MEMORY_SCOPE_AGENT) < GRID2)
      __builtin_amdgcn_s_sleep(2);
    (void)__hip_atomic_load(slot, __ATOMIC_ACQUIRE, __HIP_MEMORY_SCOPE_AGENT);
  }
  __syncthreads();
}

__device__ __forceinline__ bf16x8 cvt8(float4 a, float4 b) {
  bf16x8 r;
  r[0] = (__bf16)a.x; r[1] = (__bf16)a.y; r[2] = (__bf16)a.z; r[3] = (__bf16)a.w;
  r[4] = (__bf16)b.x; r[5] = (__bf16)b.y; r[6] = (__bf16)b.z; r[7] = (__bf16)b.w;
  return r;
}

// ================= kernel 1: scores (blocks 0..4095) + Gh (blocks 4096..5119) =================
// Gh gather-GEMM: R2-proven codepath, both operands fp32 converted inline.
__device__ __forceinline__ void gemm_acc_f32(const float* __restrict__ A,
                                             const float* __restrict__ W,
                                             int rowbase, int colbase, int lane,
                                             f32x4 acc[2][2]) {
  const int r0 = lane & 15;
  const int kl = (lane >> 4) << 3;
  const float* a0 = A + (size_t)(rowbase + r0) * 1024 + kl;
  const float* a1 = a0 + (size_t)16 * 1024;
  const float* w0 = W + (size_t)(colbase + r0) * 1024 + kl;
  const float* w1 = w0 + (size_t)16 * 1024;
#pragma unroll 4
  for (int k0 = 0; k0 < 1024; k0 += 32) {
    bf16x8 a[2], bb[2];
    a[0]  = cvt8(*(const float4*)(a0 + k0), *(const float4*)(a0 + k0 + 4));
    a[1]  = cvt8(*(const float4*)(a1 + k0), *(const float4*)(a1 + k0 + 4));
    bb[0] = cvt8(*(const float4*)(w0 + k0), *(const float4*)(w0 + k0 + 4));
    bb[1] = cvt8(*(const float4*)(w1 + k0), *(const float4*)(w1 + k0 + 4));
#pragma unroll
    for (int r = 0; r < 2; ++r)
#pragma unroll
      for (int c = 0; c < 2; ++c)
        acc[r][c] = __builtin_amdgcn_mfma_f32_16x16x32_bf16(a[r], bb[c], acc[r][c], 0, 0, 0);
  }
}

__global__ __launch_bounds__(256, 4) void k_front(
    const float* __restrict__ AO, const float* __restrict__ Wattn,
    float* __restrict__ sc,
    const float* __restrict__ h0,
    const float* __restrict__ Whh0, const float* __restrict__ Whh_r,
    const float* __restrict__ bih0, const float* __restrict__ bhh0,
    const float* __restrict__ bih_r, const float* __restrict__ bhh_r,
    float* __restrict__ Gh) {
  const int lane = threadIdx.x & 63, wave = threadIdx.x >> 6;
  if (blockIdx.x < 4096) {
    // ---- scores: sc[b*256+pos] = dot(AO[pos,b,:], w_y) (h/b terms cancel in softmax)
    const float* wy = Wattn + 1024;
    float4 wv[4];
#pragma unroll
    for (int q = 0; q < 4; ++q) wv[q] = *(const float4*)(wy + lane * 4 + 256 * q);
    const int row0 = (blockIdx.x * 4 + wave) * 4;
    float a4[4];
#pragma unroll
    for (int rr = 0; rr < 4; ++rr) {
      const float4* rp = (const float4*)(AO + (size_t)(row0 + rr) * 1024);
      float a = 0.f;
#pragma unroll
      for (int q = 0; q < 4; ++q) {
        float4 v = rp[lane + 64 * q];
        a += v.x * wv[q].x + v.y * wv[q].y + v.z * wv[q].z + v.w * wv[q].w;
      }
      a4[rr] = a;
    }
#pragma unroll
    for (int rr = 0; rr < 4; ++rr) {
      float a = a4[rr];
#pragma unroll
      for (int off = 32; off; off >>= 1) a += __shfl_xor(a, off, 64);
      if (lane == 0) {
        int row = row0 + rr;                      // row = pos*256 + b
        sc[(row & 255) * 256 + (row >> 8)] = a;   // [b][pos]
      }
    }
    return;
  }
  // ---- Gh[l] = h0[l] @ Whh[l]^T + bih + bhh (all layers; overlaps scores)
  const int j = blockIdx.x - 4096;               // 0..1023
  const int l = j >> 8, inner = j & 255;
  const int rb = inner >> 7, cb = inner & 127;
  const int rowbase = rb * 128 + wave * 32, colbase = cb * 32;
  const float* A  = h0 + (size_t)l * 262144;
  const float* W  = (l == 0) ? Whh0 : Whh_r + (size_t)(l - 1) * 4194304;
  const float* bi = (l == 0) ? bih0 : bih_r + (size_t)(l - 1) * 4096;
  const float* bh = (l == 0) ? bhh0 : bhh_r + (size_t)(l - 1) * 4096;
  f32x4 acc[2][2] = {};
  gemm_acc_f32(A, W, rowbase, colbase, lane, acc);
  float* Go = Gh + (size_t)l * 1048576;
#pragma unroll
  for (int r = 0; r < 2; ++r)
#pragma unroll
    for (int c = 0; c < 2; ++c)
#pragma unroll
      for (int q = 0; q < 4; ++q) {
        int row = rowbase + r * 16 + ((lane >> 4) << 2) + q;
        int col = colbase + c * 16 + (lane & 15);
        Go[(size_t)row * 4096 + col] = acc[r][c][q] + bi[col] + bh[col];
      }
}

// ================= kernel 2: persistent tail (grid 256) =================
// tile GEMM: 256 thr / 4 waves; tile = 64 A-rows x [16 cols x 4 gates].
// Wave w owns A-rows w*16..+15 and ALL 4 gates -> no epilogue exchange.
// Double-buffered LDS (1 sync/step), 3-deep reg prefetch, XOR-swizzled rows.
template<int K>
__device__ __forceinline__ void tile_gemm(const __bf16* __restrict__ A,
                                          const float* __restrict__ W,
                                          int r0, int j0, char* lds,
                                          f32x4 acc[4]) {
  constexpr int NK = K / 64;
  constexpr int D = 3;
  const int t = threadIdx.x, lane = t & 63, wave = t >> 6;
  const int sr = t >> 2, sc4 = t & 3;            // staging: row 0..63, 16-elem k-chunk
  const float*  wsrc = W + (size_t)((sr >> 4) * 1024 + j0 + (sr & 15)) * K + sc4 * 16;
  const __bf16* asrc = A + (size_t)(r0 + sr) * K + sc4 * 16;
  const int swz0 = (((sc4 * 2)     ^ (sr & 7)) << 4);
  const int swz1 = (((sc4 * 2 + 1) ^ (sr & 7)) << 4);
  const int arow = wave * 16 + (lane & 15);
  const int kq = lane >> 4;

  float4 wp[D][4]; bf16x8 ap[D][2];
#pragma unroll
  for (int d = 0; d < D; ++d) {
    ap[d][0] = *(const bf16x8*)(asrc + d * 64);
    ap[d][1] = *(const bf16x8*)(asrc + d * 64 + 8);
#pragma unroll
    for (int i = 0; i < 4; ++i) wp[d][i] = *(const float4*)(wsrc + d * 64 + i * 4);
  }
#pragma unroll
  for (int s = 0; s < NK; ++s) {
    const int sl = s % D;
    char* buf = lds + (s & 1) * 16384;
    *(bf16x8*)(buf + sr * 128 + swz0) = ap[sl][0];
    *(bf16x8*)(buf + sr * 128 + swz1) = ap[sl][1];
    *(bf16x8*)(buf + 8192 + sr * 128 + swz0) = cvt8(wp[sl][0], wp[sl][1]);
    *(bf16x8*)(buf + 8192 + sr * 128 + swz1) = cvt8(wp[sl][2], wp[sl][3]);
    if (s + D < NK) {
      ap[sl][0] = *(const bf16x8*)(asrc + (s + D) * 64);
      ap[sl][1] = *(const bf16x8*)(asrc + (s + D) * 64 + 8);
#pragma unroll
      for (int i = 0; i < 4; ++i) wp[sl][i] = *(const float4*)(wsrc + (s + D) * 64 + i * 4);
    }
    __syncthreads();
#pragma unroll
    for (int s2 = 0; s2 < 2; ++s2) {
      const int chk = s2 * 4 + kq;
      bf16x8 af = *(const bf16x8*)(buf + arow * 128 + ((chk ^ (arow & 7)) << 4));
#pragma unroll
      for (int g = 0; g < 4; ++g) {
        const int wrow = g * 16 + (lane & 15);
        bf16x8 wf = *(const bf16x8*)(buf + 8192 + wrow * 128 + ((chk ^ (wrow & 7)) << 4));
        acc[g] = __builtin_amdgcn_mfma_f32_16x16x32_bf16(af, wf, acc[g], 0, 0, 0);
      }
    }
  }
}

__device__ __forceinline__ void gates_ep(f32x4 acc[4], const float* __restrict__ Ghl,
                                         const float* __restrict__ c0l,
                                         float* __restrict__ h_out,
                                         float* __restrict__ c_out,
                                         __bf16* __restrict__ hb_out,
                                         int r0, int j0, int lane, int wave) {
  const int col = j0 + (lane & 15);
  const int rbase = r0 + wave * 16 + ((lane >> 4) << 2);
#pragma unroll
  for (int g = 0; g < 4; ++g)
#pragma unroll
    for (int q = 0; q < 4; ++q)
      acc[g][q] += Ghl[(size_t)(rbase + q) * 4096 + g * 1024 + col];
#pragma unroll
  for (int q = 0; q < 4; ++q) {
    const int row = rbase + q;
    float si = 1.f / (1.f + __expf(-acc[0][q]));
    float sf = 1.f / (1.f + __expf(-acc[1][q]));
    float gv = tanhf(acc[2][q]);
    float so = 1.f / (1.f + __expf(-acc[3][q]));
    float c2 = sf * c0l[(size_t)row * 1024 + col] + si * gv;
    float h2 = so * tanhf(c2);
    h_out[(size_t)row * 1024 + col] = h2;
    c_out[(size_t)row * 1024 + col] = c2;
    hb_out[(size_t)row * 1024 + col] = (__bf16)h2;
  }
}

__global__ __launch_bounds__(256) void k_tail(
    const float* __restrict__ inp,  const float* __restrict__ c0,
    const float* __restrict__ AO,
    const float* __restrict__ Wemb, const float* __restrict__ bemb,
    const float* __restrict__ Wih0, const float* __restrict__ Wih_r,
    const float* __restrict__ Wout, const float* __restrict__ bout,
    const float* __restrict__ sc,   const float* __restrict__ Gh,
    float* __restrict__ out, int* __restrict__ bar,
    __bf16* __restrict__ xb, __bf16* __restrict__ hb) {
  __shared__ char smem[32768];
  const int t = threadIdx.x, lane = t & 63, wave = t >> 6;

  // ---- phase 1: softmax + applied_last + embedding -> xb (one block per b)
  {
    const int b = blockIdx.x;
    float* red = (float*)smem;
    float s = sc[b * 256 + t];
    float m = s;
#pragma unroll
    for (int off = 32; off; off >>= 1) m = fmaxf(m, __shfl_xor(m, off, 64));
    if (lane == 0) red[wave] = m;
    __syncthreads();
    m = fmaxf(fmaxf(red[0], red[1]), fmaxf(red[2], red[3]));
    float e = __expf(s - m);
    float sum = e;
#pragma unroll
    for (int off = 32; off; off >>= 1) sum += __shfl_xor(sum, off, 64);
    __syncthreads();
    if (lane == 0) red[wave] = sum;
    __syncthreads();
    sum = red[0] + red[1] + red[2] + red[3];
    float nv = e / sum;
    out[O_NORM + b * 256 + t] = nv;
    float* nv_l = (float*)(smem + 64);
    if (t >= 224) nv_l[t - 224] = nv;
    __syncthreads();
    float a0 = 0.f, a1 = 0.f, a2 = 0.f, a3 = 0.f;
    const float* base = AO + ((size_t)224 * 256 + b) * 1024;
#pragma unroll 4
    for (int i = 0; i < 32; ++i) {
      float w = nv_l[i];
      const float* rp = base + (size_t)i * 262144;
      a0 += w * rp[t];
      a1 += w * rp[t + 256];
      a2 += w * rp[t + 512];
      a3 += w * rp[t + 768];
    }
    xb[(size_t)b * 1536 + t]       = (__bf16)(8.0f * a0);
    xb[(size_t)b * 1536 + t + 256] = (__bf16)(8.0f * a1);
    xb[(size_t)b * 1536 + t + 512] = (__bf16)(8.0f * a2);
    xb[(size_t)b * 1536 + t + 768] = (__bf16)(8.0f * a3);
#pragma unroll
    for (int r = 0; r < 2; ++r) {
      int jj = t + 256 * r;
      float e2 = inp[b * 2] * Wemb[jj * 2] + inp[b * 2 + 1] * Wemb[jj * 2 + 1] + bemb[jj];
      xb[(size_t)b * 1536 + 1024 + jj] = (__bf16)fmaxf(e2, 0.f);
    }
  }
  gridbar(bar + 0 * 32);

  // ---- layers (256 blocks: 64 col-strips x 4 row-blocks)
  const int cb = blockIdx.x & 63, rb = blockIdx.x >> 6;
  const int j0 = cb * 16, r0 = rb * 64;
  {
    f32x4 acc[4] = {};
    tile_gemm<1536>(xb, Wih0, r0, j0, smem, acc);
    gates_ep(acc, Gh, c0, out + O_H, out + O_C, hb, r0, j0, lane, wave);
  }
  gridbar(bar + 1 * 32);
#pragma unroll 1
  for (int l = 1; l < 4; ++l) {
    f32x4 acc[4] = {};
    tile_gemm<1024>(hb + (size_t)(l - 1) * 262144,
                    Wih_r + (size_t)(l - 1) * 4194304, r0, j0, smem, acc);
    gates_ep(acc, Gh + (size_t)l * 1048576, c0 + (size_t)l * 262144,
             out + O_H + (size_t)l * 262144, out + O_C + (size_t)l * 262144,
             hb + (size_t)l * 262144, r0, j0, lane, wave);
    gridbar(bar + (l + 1) * 32);
  }

  // ---- final: out[b,:2] = h3[b,:] @ Wout^T + bout
  if (blockIdx.x < 64) {
    const float* h3 = out + O_H + 3 * 262144;
    const int bb = blockIdx.x * 4 + wave;
    const float4* hp = (const float4*)(h3 + (size_t)bb * 1024);
    const float4* w0 = (const float4*)Wout;
    const float4* w1 = (const float4*)(Wout + 1024);
    float a0 = 0.f, a1 = 0.f;
#pragma unroll
    for (int q = 0; q < 4; ++q) {
      float4 hv = hp[lane + 64 * q];
      float4 v0 = w0[lane + 64 * q];
      float4 v1 = w1[lane + 64 * q];
      a0 += hv.x * v0.x + hv.y * v0.y + hv.z * v0.z + hv.w * v0.w;
      a1 += hv.x * v1.x + hv.y * v1.y + hv.z * v1.z + hv.w * v1.w;
    }
#pragma unroll
    for (int off = 32; off; off >>= 1) {
      a0 += __shfl_xor(a0, off, 64);
      a1 += __shfl_xor(a1, off, 64);
    }
    if (lane == 0) {
      out[bb * 2]     = a0 + bout[0];
      out[bb * 2 + 1] = a1 + bout[1];
    }
  }
}

extern "C" void kernel_launch(void* const* d_in, const int* in_sizes, int n_in,
                              void* d_out, int out_size, void* d_ws, size_t ws_size,
                              hipStream_t stream) {
  const float* inp    = (const float*)d_in[0];
  const float* h0     = (const float*)d_in[1];
  const float* c0     = (const float*)d_in[2];
  const float* AO     = (const float*)d_in[3];
  const float* Wemb   = (const float*)d_in[4];
  const float* bemb   = (const float*)d_in[5];
  const float* Wattn  = (const float*)d_in[6];
  // d_in[7] = b_attn (cancels in softmax)
  const float* Wih0   = (const float*)d_in[8];
  const float* Whh0   = (const float*)d_in[9];
  const float* bih0   = (const float*)d_in[10];
  const float* bhh0   = (const float*)d_in[11];
  const float* Wih_r  = (const float*)d_in[12];
  const float* Whh_r  = (const float*)d_in[13];
  const float* bih_r  = (const float*)d_in[14];
  const float* bhh_r  = (const float*)d_in[15];
  const float* Wout   = (const float*)d_in[16];
  const float* bout   = (const float*)d_in[17];

  float* out = (float*)d_out;
  char* ws = (char*)d_ws;

  int*    bar = (int*)ws;                         // 4 KB barrier slots
  float*  sc  = (float*)(ws + 4096);              // 256 KB [256][256]
  float*  Gh  = (float*)(ws + 266240);            // 16 MB [4][256][4096]
  __bf16* xb  = (__bf16*)(ws + 17043456);         // 768 KB [256][1536]
  __bf16* hb  = (__bf16*)(ws + 17829888);         // 2 MB [4][256][1024]

  hipMemsetAsync(bar, 0, 4096, stream);
  k_front<<<5120, 256, 0, stream>>>(AO, Wattn, sc, h0, Whh0, Whh_r,
                                    bih0, bhh0, bih_r, bhh_r, Gh);
  k_tail<<<256, 256, 0, stream>>>(inp, c0, AO, Wemb, bemb, Wih0, Wih_r,
                                  Wout, bout, sc, Gh, out, bar, xb, hb);
}

// Round 8
// 166.297 us; speedup vs baseline: 2.1697x; 2.1697x over previous
//
#include <hip/hip_runtime.h>
#include <hip/hip_bf16.h>

typedef __bf16 bf16x8 __attribute__((ext_vector_type(8)));
typedef __bf16 bf16x4 __attribute__((ext_vector_type(4)));
typedef float  f32x4  __attribute__((ext_vector_type(4)));

// d_out offsets (floats)
#define O_FINAL 0
#define O_H     512
#define O_C     1049088      // 512 + 4*256*1024
#define O_NORM  2097664      // O_C + 4*256*1024

__device__ __forceinline__ bf16x8 cvt8(float4 a, float4 b) {
  bf16x8 r;
  r[0] = (__bf16)a.x; r[1] = (__bf16)a.y; r[2] = (__bf16)a.z; r[3] = (__bf16)a.w;
  r[4] = (__bf16)b.x; r[5] = (__bf16)b.y; r[6] = (__bf16)b.z; r[7] = (__bf16)b.w;
  return r;
}

// ============ R3-proven staged tile GEMM (512 thr, 8 waves) ============
// Tile: 64 A-rows x [16 cols x 4 gates]. Wave w: rf=w&3 row-frag, gg=w>>2
// gate-pair. XOR-swizzled LDS rows (128B), 1-deep reg prefetch, 2 sync/step.
// _ff: A fp32, W fp32 (both cvt during staging)  -- for Gh
// _bb: A bf16, W bf16 (pure copy staging)        -- for layers
template<int K>
__device__ __forceinline__ void tile_gemm_ff(const float* __restrict__ A,
                                             const float* __restrict__ W,
                                             int r0, int j0,
                                             __bf16* __restrict__ At,
                                             __bf16* __restrict__ Wt,
                                             f32x4 acc[2]) {
  const int t = threadIdx.x, lane = t & 63, wave = t >> 6;
  const int rf = wave & 3, gg = wave >> 2;
  const int tr = t >> 3, chunk = t & 7;
  const float* wsrc = W + (size_t)((tr >> 4) * 1024 + j0 + (tr & 15)) * K + chunk * 8;
  const float* asrc = A + (size_t)(r0 + tr) * K + chunk * 8;
  const int sw_off = (chunk ^ (tr & 7)) << 4;
  char* wdst = (char*)Wt + tr * 128 + sw_off;
  char* adst = (char*)At + tr * 128 + sw_off;
  const int a_tr  = rf * 16 + (lane & 15);
  const int w_tr0 = gg * 32 + (lane & 15);
  const int w_tr1 = w_tr0 + 16;
  const int ksel  = lane >> 4;

  float4 wr0 = *(const float4*)wsrc, wr1 = *(const float4*)(wsrc + 4);
  float4 ar0 = *(const float4*)asrc, ar1 = *(const float4*)(asrc + 4);

  constexpr int NK = K / 64;
#pragma unroll 2
  for (int step = 0; step < NK; ++step) {
    __syncthreads();
    *(bf16x8*)wdst = cvt8(wr0, wr1);
    *(bf16x8*)adst = cvt8(ar0, ar1);
    __syncthreads();
    if (step + 1 < NK) {
      wr0 = *(const float4*)(wsrc + (step + 1) * 64);
      wr1 = *(const float4*)(wsrc + (step + 1) * 64 + 4);
      ar0 = *(const float4*)(asrc + (step + 1) * 64);
      ar1 = *(const float4*)(asrc + (step + 1) * 64 + 4);
    }
#pragma unroll
    for (int s = 0; s < 2; ++s) {
      const int chk = s * 4 + ksel;
      bf16x8 af  = *(const bf16x8*)((char*)At + a_tr  * 128 + ((chk ^ (a_tr  & 7)) << 4));
      bf16x8 wf0 = *(const bf16x8*)((char*)Wt + w_tr0 * 128 + ((chk ^ (w_tr0 & 7)) << 4));
      bf16x8 wf1 = *(const bf16x8*)((char*)Wt + w_tr1 * 128 + ((chk ^ (w_tr1 & 7)) << 4));
      acc[0] = __builtin_amdgcn_mfma_f32_16x16x32_bf16(af, wf0, acc[0], 0, 0, 0);
      acc[1] = __builtin_amdgcn_mfma_f32_16x16x32_bf16(af, wf1, acc[1], 0, 0, 0);
    }
  }
}

template<int K>
__device__ __forceinline__ void tile_gemm_bb(const __bf16* __restrict__ A,
                                             const __bf16* __restrict__ W,
                                             int r0, int j0,
                                             __bf16* __restrict__ At,
                                             __bf16* __restrict__ Wt,
                                             f32x4 acc[2]) {
  const int t = threadIdx.x, lane = t & 63, wave = t >> 6;
  const int rf = wave & 3, gg = wave >> 2;
  const int tr = t >> 3, chunk = t & 7;
  const __bf16* wsrc = W + (size_t)((tr >> 4) * 1024 + j0 + (tr & 15)) * K + chunk * 8;
  const __bf16* asrc = A + (size_t)(r0 + tr) * K + chunk * 8;
  const int sw_off = (chunk ^ (tr & 7)) << 4;
  char* wdst = (char*)Wt + tr * 128 + sw_off;
  char* adst = (char*)At + tr * 128 + sw_off;
  const int a_tr  = rf * 16 + (lane & 15);
  const int w_tr0 = gg * 32 + (lane & 15);
  const int w_tr1 = w_tr0 + 16;
  const int ksel  = lane >> 4;

  bf16x8 wr = *(const bf16x8*)wsrc;
  bf16x8 ar = *(const bf16x8*)asrc;

  constexpr int NK = K / 64;
#pragma unroll 2
  for (int step = 0; step < NK; ++step) {
    __syncthreads();
    *(bf16x8*)wdst = wr;
    *(bf16x8*)adst = ar;
    __syncthreads();
    if (step + 1 < NK) {
      wr = *(const bf16x8*)(wsrc + (step + 1) * 64);
      ar = *(const bf16x8*)(asrc + (step + 1) * 64);
    }
#pragma unroll
    for (int s = 0; s < 2; ++s) {
      const int chk = s * 4 + ksel;
      bf16x8 af  = *(const bf16x8*)((char*)At + a_tr  * 128 + ((chk ^ (a_tr  & 7)) << 4));
      bf16x8 wf0 = *(const bf16x8*)((char*)Wt + w_tr0 * 128 + ((chk ^ (w_tr0 & 7)) << 4));
      bf16x8 wf1 = *(const bf16x8*)((char*)Wt + w_tr1 * 128 + ((chk ^ (w_tr1 & 7)) << 4));
      acc[0] = __builtin_amdgcn_mfma_f32_16x16x32_bf16(af, wf0, acc[0], 0, 0, 0);
      acc[1] = __builtin_amdgcn_mfma_f32_16x16x32_bf16(af, wf1, acc[1], 0, 0, 0);
    }
  }
}

// ============ k_front: scores | LDS-staged Gh | Wih fp32->bf16 ============
__global__ __launch_bounds__(512) void k_front(
    const float* __restrict__ AO, const float* __restrict__ Wattn,
    float* __restrict__ sc,
    const float* __restrict__ h0,
    const float* __restrict__ Whh0, const float* __restrict__ Whh_r,
    const float* __restrict__ bih0, const float* __restrict__ bhh0,
    const float* __restrict__ bih_r, const float* __restrict__ bhh_r,
    float* __restrict__ Gh,
    const float* __restrict__ Wih0, const float* __restrict__ Wih_r,
    __bf16* __restrict__ Wihb) {
  const int t = threadIdx.x, lane = t & 63, wave = t >> 6;
  if (blockIdx.x < 2048) {
    // ---- scores: sc[b*256+pos] = dot(AO[pos,b,:], w_y) (h/b terms cancel in softmax)
    const float* wy = Wattn + 1024;
    float4 wv[4];
#pragma unroll
    for (int q = 0; q < 4; ++q) wv[q] = *(const float4*)(wy + lane * 4 + 256 * q);
    const int row0 = (blockIdx.x * 8 + wave) * 4;
    float a4[4];
#pragma unroll
    for (int rr = 0; rr < 4; ++rr) {
      const float4* rp = (const float4*)(AO + (size_t)(row0 + rr) * 1024);
      float a = 0.f;
#pragma unroll
      for (int q = 0; q < 4; ++q) {
        float4 v = rp[lane + 64 * q];
        a += v.x * wv[q].x + v.y * wv[q].y + v.z * wv[q].z + v.w * wv[q].w;
      }
      a4[rr] = a;
    }
#pragma unroll
    for (int rr = 0; rr < 4; ++rr) {
      float a = a4[rr];
#pragma unroll
      for (int off = 32; off; off >>= 1) a += __shfl_xor(a, off, 64);
      if (lane == 0) {
        int row = row0 + rr;                      // row = pos*256 + b
        sc[(row & 255) * 256 + (row >> 8)] = a;   // [b][pos]
      }
    }
    return;
  }
  if (blockIdx.x < 3072) {
    // ---- Gh[l] = h0[l] @ Whh[l]^T + bih + bhh (LDS-staged, fp32 operands)
    __shared__ __bf16 At[64 * 64];
    __shared__ __bf16 Wt[64 * 64];
    const int j = blockIdx.x - 2048;
    const int l = j >> 8, inner = j & 255;
    const int cb = inner & 63, rb = inner >> 6;
    const int j0 = cb * 16, r0 = rb * 64;
    const float* A  = h0 + (size_t)l * 262144;
    const float* W  = (l == 0) ? Whh0 : (Whh_r + (size_t)(l - 1) * 4194304);
    const float* bi = (l == 0) ? bih0 : (bih_r + (size_t)(l - 1) * 4096);
    const float* bh = (l == 0) ? bhh0 : (bhh_r + (size_t)(l - 1) * 4096);
    f32x4 acc[2] = {};
    tile_gemm_ff<1024>(A, W, r0, j0, At, Wt, acc);
    float* Go = Gh + (size_t)l * 1048576;
    const int rf = wave & 3, gg = wave >> 2;
    const int col = j0 + (lane & 15);
    const int rbase = r0 + rf * 16 + ((lane >> 4) << 2);
#pragma unroll
    for (int gi = 0; gi < 2; ++gi) {
      const int cg = (gg * 2 + gi) * 1024 + col;
#pragma unroll
      for (int q = 0; q < 4; ++q)
        Go[(size_t)(rbase + q) * 4096 + cg] = acc[gi][q] + bi[cg] + bh[cg];
    }
    return;
  }
  // ---- Wih fp32 -> bf16  (Wihb = [Wih0b (6291456) | Wih_rb (12582912)])
  const int tid = ((int)blockIdx.x - 3072) * 512 + t;    // 0..589823
#pragma unroll
  for (int n = 0; n < 8; ++n) {
    int idx = tid + n * 589824;                          // float4 index, 4718592 total
    float4 v = (idx < 1572864) ? ((const float4*)Wih0)[idx]
                               : ((const float4*)Wih_r)[idx - 1572864];
    bf16x4 o;
    o[0] = (__bf16)v.x; o[1] = (__bf16)v.y; o[2] = (__bf16)v.z; o[3] = (__bf16)v.w;
    ((bf16x4*)Wihb)[idx] = o;
  }
}

// ============ k_smx: softmax + applied_last + embedding -> xb ============
__global__ __launch_bounds__(256) void k_smx(const float* __restrict__ sc,
                                             const float* __restrict__ AO,
                                             const float* __restrict__ inp,
                                             const float* __restrict__ Wemb,
                                             const float* __restrict__ bemb,
                                             float* __restrict__ norm_out,
                                             __bf16* __restrict__ x) {
  __shared__ float red[4];
  __shared__ float wsm[32];
  const int b = blockIdx.x, t = threadIdx.x, lane = t & 63, wave = t >> 6;
  float s = sc[b * 256 + t];
  float m = s;
#pragma unroll
  for (int off = 32; off; off >>= 1) m = fmaxf(m, __shfl_xor(m, off, 64));
  if (lane == 0) red[wave] = m;
  __syncthreads();
  m = fmaxf(fmaxf(red[0], red[1]), fmaxf(red[2], red[3]));
  float e = __expf(s - m);
  float sum = e;
#pragma unroll
  for (int off = 32; off; off >>= 1) sum += __shfl_xor(sum, off, 64);
  __syncthreads();
  if (lane == 0) red[wave] = sum;
  __syncthreads();
  sum = red[0] + red[1] + red[2] + red[3];
  float nv = e / sum;
  norm_out[b * 256 + t] = nv;
  if (t >= 224) wsm[t - 224] = nv;
  __syncthreads();
  float acc[4] = {0.f, 0.f, 0.f, 0.f};
  const float* base = AO + ((size_t)224 * 256 + b) * 1024;
#pragma unroll 4
  for (int i = 0; i < 32; ++i) {
    float w = wsm[i];
    const float* rp = base + (size_t)i * 262144;
#pragma unroll
    for (int q = 0; q < 4; ++q) acc[q] += w * rp[t + 256 * q];
  }
#pragma unroll
  for (int q = 0; q < 4; ++q) x[(size_t)b * 1536 + t + 256 * q] = (__bf16)(8.0f * acc[q]);
  float i0 = inp[b * 2], i1 = inp[b * 2 + 1];
#pragma unroll
  for (int r = 0; r < 2; ++r) {
    int jj = t + 256 * r;
    float e2 = i0 * Wemb[jj * 2] + i1 * Wemb[jj * 2 + 1] + bemb[jj];
    x[(size_t)b * 1536 + 1024 + jj] = (__bf16)fmaxf(e2, 0.f);
  }
}

// ============ k_layer: GEMM (bf16 W) + Gh add + gates ============
template<int K>
__global__ __launch_bounds__(512) void k_layer(const __bf16* __restrict__ A,
                                               const __bf16* __restrict__ Wb,
                                               const float* __restrict__ Gh,
                                               const float* __restrict__ c0l,
                                               float* __restrict__ h_out,
                                               float* __restrict__ c_out,
                                               __bf16* __restrict__ hb) {
  __shared__ __bf16 At[64 * 64];
  __shared__ __bf16 Wt[64 * 64];
  __shared__ float exch[4][2][256];
  const int t = threadIdx.x, lane = t & 63, wave = t >> 6;
  const int rf = wave & 3, gg = wave >> 2;
  const int cb = blockIdx.x & 63, rb = blockIdx.x >> 6;
  const int j0 = cb * 16, r0 = rb * 64;
  f32x4 acc[2] = {};
  tile_gemm_bb<K>(A, Wb, r0, j0, At, Wt, acc);
  const int col = j0 + (lane & 15);
  const int rbase = r0 + rf * 16 + ((lane >> 4) << 2);
#pragma unroll
  for (int gi = 0; gi < 2; ++gi) {
    const float* gp = Gh + (size_t)rbase * 4096 + (gg * 2 + gi) * 1024 + col;
#pragma unroll
    for (int q = 0; q < 4; ++q) acc[gi][q] += gp[(size_t)q * 4096];
  }
  const int eidx = ((lane >> 4) << 2) * 16 + (lane & 15);
  if (gg == 1) {
#pragma unroll
    for (int gi = 0; gi < 2; ++gi)
#pragma unroll
      for (int q = 0; q < 4; ++q)
        exch[rf][gi][eidx + q * 16] = acc[gi][q];
  }
  __syncthreads();
  if (gg == 0) {
#pragma unroll
    for (int q = 0; q < 4; ++q) {
      const int row = rbase + q;
      float gv = exch[rf][0][eidx + q * 16];
      float ov = exch[rf][1][eidx + q * 16];
      float si = 1.f / (1.f + __expf(-acc[0][q]));
      float sf = 1.f / (1.f + __expf(-acc[1][q]));
      float so = 1.f / (1.f + __expf(-ov));
      float c2 = sf * c0l[(size_t)row * 1024 + col] + si * tanhf(gv);
      float h2 = so * tanhf(c2);
      h_out[(size_t)row * 1024 + col] = h2;
      c_out[(size_t)row * 1024 + col] = c2;
      hb[(size_t)row * 1024 + col] = (__bf16)h2;
    }
  }
}

// ============ k_final ============
__global__ __launch_bounds__(256) void k_final(const float* __restrict__ h3,
                                               const float* __restrict__ Wout,
                                               const float* __restrict__ bout,
                                               float* __restrict__ out) {
  const int lane = threadIdx.x & 63, wave = threadIdx.x >> 6;
  const int b = blockIdx.x * 4 + wave;
  const float4* hp = (const float4*)(h3 + (size_t)b * 1024);
  const float4* w0 = (const float4*)Wout;
  const float4* w1 = (const float4*)(Wout + 1024);
  float a0 = 0.f, a1 = 0.f;
#pragma unroll
  for (int q = 0; q < 4; ++q) {
    float4 hv = hp[lane + 64 * q];
    float4 v0 = w0[lane + 64 * q];
    float4 v1 = w1[lane + 64 * q];
    a0 += hv.x * v0.x + hv.y * v0.y + hv.z * v0.z + hv.w * v0.w;
    a1 += hv.x * v1.x + hv.y * v1.y + hv.z * v1.z + hv.w * v1.w;
  }
#pragma unroll
  for (int off = 32; off; off >>= 1) {
    a0 += __shfl_xor(a0, off, 64);
    a1 += __shfl_xor(a1, off, 64);
  }
  if (lane == 0) {
    out[b * 2]     = a0 + bout[0];
    out[b * 2 + 1] = a1 + bout[1];
  }
}

extern "C" void kernel_launch(void* const* d_in, const int* in_sizes, int n_in,
                              void* d_out, int out_size, void* d_ws, size_t ws_size,
                              hipStream_t stream) {
  const float* inp    = (const float*)d_in[0];
  const float* h0     = (const float*)d_in[1];
  const float* c0     = (const float*)d_in[2];
  const float* AO     = (const float*)d_in[3];
  const float* Wemb   = (const float*)d_in[4];
  const float* bemb   = (const float*)d_in[5];
  const float* Wattn  = (const float*)d_in[6];
  // d_in[7] = b_attn (cancels in softmax)
  const float* Wih0   = (const float*)d_in[8];
  const float* Whh0   = (const float*)d_in[9];
  const float* bih0   = (const float*)d_in[10];
  const float* bhh0   = (const float*)d_in[11];
  const float* Wih_r  = (const float*)d_in[12];
  const float* Whh_r  = (const float*)d_in[13];
  const float* bih_r  = (const float*)d_in[14];
  const float* bhh_r  = (const float*)d_in[15];
  const float* Wout   = (const float*)d_in[16];
  const float* bout   = (const float*)d_in[17];

  float* out = (float*)d_out;
  char* ws = (char*)d_ws;

  __bf16* Wihb  = (__bf16*)ws;                         // 36 MB bf16 [Wih0b|Wih_rb]
  float*  Gh    = (float*)(ws + 37748736);             // 16 MB [4][256][4096]
  __bf16* xb    = (__bf16*)(ws + 54525952);            // 768 KB [256][1536]
  __bf16* hb    = (__bf16*)(ws + 55312384);            // 2 MB [4][256][1024]
  float*  sc    = (float*)(ws + 57409536);             // 256 KB [256][256]
  __bf16* Wihb0 = Wihb;
  __bf16* Wihbr = Wihb + 6291456;

  k_front<<<4224, 512, 0, stream>>>(AO, Wattn, sc, h0, Whh0, Whh_r,
                                    bih0, bhh0, bih_r, bhh_r, Gh,
                                    Wih0, Wih_r, Wihb);
  k_smx<<<256, 256, 0, stream>>>(sc, AO, inp, Wemb, bemb, out + O_NORM, xb);

  k_layer<1536><<<256, 512, 0, stream>>>(xb, Wihb0, Gh, c0,
                                         out + O_H, out + O_C, hb);
  for (int l = 1; l < 4; ++l)
    k_layer<1024><<<256, 512, 0, stream>>>(hb + (size_t)(l - 1) * 262144,
                                           Wihbr + (size_t)(l - 1) * 4194304,
                                           Gh + (size_t)l * 1048576,
                                           c0 + (size_t)l * 262144,
                                           out + O_H + (size_t)l * 262144,
                                           out + O_C + (size_t)l * 262144,
                                           hb + (size_t)l * 262144);

  k_final<<<64, 256, 0, stream>>>(out + O_H + 3 * 262144, Wout, bout, out + O_FINAL);
}

// Round 9
// 154.059 us; speedup vs baseline: 2.3421x; 1.0794x over previous
//
#include <hip/hip_runtime.h>
#include <hip/hip_bf16.h>

typedef __bf16 bf16x8 __attribute__((ext_vector_type(8)));
typedef __bf16 bf16x4 __attribute__((ext_vector_type(4)));
typedef float  f32x4  __attribute__((ext_vector_type(4)));

// d_out offsets (floats)
#define O_FINAL 0
#define O_H     512
#define O_C     1049088      // 512 + 4*256*1024
#define O_NORM  2097664      // O_C + 4*256*1024

__device__ __forceinline__ bf16x8 cvt8(float4 a, float4 b) {
  bf16x8 r;
  r[0] = (__bf16)a.x; r[1] = (__bf16)a.y; r[2] = (__bf16)a.z; r[3] = (__bf16)a.w;
  r[4] = (__bf16)b.x; r[5] = (__bf16)b.y; r[6] = (__bf16)b.z; r[7] = (__bf16)b.w;
  return r;
}

// ============ staged tile GEMM v2 (512 thr, 8 waves) ============
// Tile: 64 A-rows x [16 cols x 4 gates]. Wave w: rf=w&3 row-frag, gg=w>>2
// gate-pair. XOR-swizzled LDS rows (128B). Double-buffered LDS, ONE
// __syncthreads per K-step, 4-deep register prefetch (slack ~4 steps covers
// ~900cy HBM latency). Race-free: wave's compute(s) precedes its write(s+1)
// in program order, so the s+1 barrier orders compute(s) before write(s+2)
// touches the same buffer.
// _bb: A bf16, W bf16 (layers)   _ff: A fp32, W fp32 (Gh)
template<int K>
__device__ __forceinline__ void tile_gemm_bb(const __bf16* __restrict__ A,
                                             const __bf16* __restrict__ W,
                                             int r0, int j0, char* lds,
                                             f32x4 acc[2]) {
  constexpr int NK = K / 64;
  constexpr int D = 4;
  const int t = threadIdx.x, lane = t & 63, wave = t >> 6;
  const int rf = wave & 3, gg = wave >> 2;
  const int tr = t >> 3, chunk = t & 7;
  const __bf16* wsrc = W + (size_t)((tr >> 4) * 1024 + j0 + (tr & 15)) * K + chunk * 8;
  const __bf16* asrc = A + (size_t)(r0 + tr) * K + chunk * 8;
  const int sw_off = (chunk ^ (tr & 7)) << 4;
  const int woff = 8192 + tr * 128 + sw_off;
  const int aoff = tr * 128 + sw_off;
  const int a_tr  = rf * 16 + (lane & 15);
  const int w_tr0 = gg * 32 + (lane & 15);
  const int w_tr1 = w_tr0 + 16;
  const int ksel  = lane >> 4;

  bf16x8 wp[D], ap[D];
#pragma unroll
  for (int d = 0; d < D; ++d) {
    wp[d] = *(const bf16x8*)(wsrc + d * 64);
    ap[d] = *(const bf16x8*)(asrc + d * 64);
  }
#pragma unroll
  for (int s = 0; s < NK; ++s) {
    const int sl = s % D;
    char* buf = lds + (s & 1) * 16384;
    *(bf16x8*)(buf + aoff) = ap[sl];
    *(bf16x8*)(buf + woff) = wp[sl];
    if (s + D < NK) {
      wp[sl] = *(const bf16x8*)(wsrc + (s + D) * 64);
      ap[sl] = *(const bf16x8*)(asrc + (s + D) * 64);
    }
    __syncthreads();
#pragma unroll
    for (int s2 = 0; s2 < 2; ++s2) {
      const int chk = s2 * 4 + ksel;
      bf16x8 af  = *(const bf16x8*)(buf + a_tr * 128 + ((chk ^ (a_tr & 7)) << 4));
      bf16x8 wf0 = *(const bf16x8*)(buf + 8192 + w_tr0 * 128 + ((chk ^ (w_tr0 & 7)) << 4));
      bf16x8 wf1 = *(const bf16x8*)(buf + 8192 + w_tr1 * 128 + ((chk ^ (w_tr1 & 7)) << 4));
      acc[0] = __builtin_amdgcn_mfma_f32_16x16x32_bf16(af, wf0, acc[0], 0, 0, 0);
      acc[1] = __builtin_amdgcn_mfma_f32_16x16x32_bf16(af, wf1, acc[1], 0, 0, 0);
    }
  }
}

template<int K>
__device__ __forceinline__ void tile_gemm_ff(const float* __restrict__ A,
                                             const float* __restrict__ W,
                                             int r0, int j0, char* lds,
                                             f32x4 acc[2]) {
  constexpr int NK = K / 64;
  constexpr int D = 4;
  const int t = threadIdx.x, lane = t & 63, wave = t >> 6;
  const int rf = wave & 3, gg = wave >> 2;
  const int tr = t >> 3, chunk = t & 7;
  const float* wsrc = W + (size_t)((tr >> 4) * 1024 + j0 + (tr & 15)) * K + chunk * 8;
  const float* asrc = A + (size_t)(r0 + tr) * K + chunk * 8;
  const int sw_off = (chunk ^ (tr & 7)) << 4;
  const int woff = 8192 + tr * 128 + sw_off;
  const int aoff = tr * 128 + sw_off;
  const int a_tr  = rf * 16 + (lane & 15);
  const int w_tr0 = gg * 32 + (lane & 15);
  const int w_tr1 = w_tr0 + 16;
  const int ksel  = lane >> 4;

  float4 wp[D][2], ap[D][2];
#pragma unroll
  for (int d = 0; d < D; ++d) {
    wp[d][0] = *(const float4*)(wsrc + d * 64);
    wp[d][1] = *(const float4*)(wsrc + d * 64 + 4);
    ap[d][0] = *(const float4*)(asrc + d * 64);
    ap[d][1] = *(const float4*)(asrc + d * 64 + 4);
  }
#pragma unroll
  for (int s = 0; s < NK; ++s) {
    const int sl = s % D;
    char* buf = lds + (s & 1) * 16384;
    *(bf16x8*)(buf + aoff) = cvt8(ap[sl][0], ap[sl][1]);
    *(bf16x8*)(buf + woff) = cvt8(wp[sl][0], wp[sl][1]);
    if (s + D < NK) {
      wp[sl][0] = *(const float4*)(wsrc + (s + D) * 64);
      wp[sl][1] = *(const float4*)(wsrc + (s + D) * 64 + 4);
      ap[sl][0] = *(const float4*)(asrc + (s + D) * 64);
      ap[sl][1] = *(const float4*)(asrc + (s + D) * 64 + 4);
    }
    __syncthreads();
#pragma unroll
    for (int s2 = 0; s2 < 2; ++s2) {
      const int chk = s2 * 4 + ksel;
      bf16x8 af  = *(const bf16x8*)(buf + a_tr * 128 + ((chk ^ (a_tr & 7)) << 4));
      bf16x8 wf0 = *(const bf16x8*)(buf + 8192 + w_tr0 * 128 + ((chk ^ (w_tr0 & 7)) << 4));
      bf16x8 wf1 = *(const bf16x8*)(buf + 8192 + w_tr1 * 128 + ((chk ^ (w_tr1 & 7)) << 4));
      acc[0] = __builtin_amdgcn_mfma_f32_16x16x32_bf16(af, wf0, acc[0], 0, 0, 0);
      acc[1] = __builtin_amdgcn_mfma_f32_16x16x32_bf16(af, wf1, acc[1], 0, 0, 0);
    }
  }
}

// ============ k_front: scores | LDS-staged Gh | Wih fp32->bf16 ============
__global__ __launch_bounds__(512) void k_front(
    const float* __restrict__ AO, const float* __restrict__ Wattn,
    float* __restrict__ sc,
    const float* __restrict__ h0,
    const float* __restrict__ Whh0, const float* __restrict__ Whh_r,
    const float* __restrict__ bih0, const float* __restrict__ bhh0,
    const float* __restrict__ bih_r, const float* __restrict__ bhh_r,
    float* __restrict__ Gh,
    const float* __restrict__ Wih0, const float* __restrict__ Wih_r,
    __bf16* __restrict__ Wihb) {
  const int t = threadIdx.x, lane = t & 63, wave = t >> 6;
  if (blockIdx.x < 2048) {
    // ---- scores: sc[b*256+pos] = dot(AO[pos,b,:], w_y) (h/b terms cancel in softmax)
    const float* wy = Wattn + 1024;
    float4 wv[4];
#pragma unroll
    for (int q = 0; q < 4; ++q) wv[q] = *(const float4*)(wy + lane * 4 + 256 * q);
    const int row0 = (blockIdx.x * 8 + wave) * 4;
    float a4[4];
#pragma unroll
    for (int rr = 0; rr < 4; ++rr) {
      const float4* rp = (const float4*)(AO + (size_t)(row0 + rr) * 1024);
      float a = 0.f;
#pragma unroll
      for (int q = 0; q < 4; ++q) {
        float4 v = rp[lane + 64 * q];
        a += v.x * wv[q].x + v.y * wv[q].y + v.z * wv[q].z + v.w * wv[q].w;
      }
      a4[rr] = a;
    }
#pragma unroll
    for (int rr = 0; rr < 4; ++rr) {
      float a = a4[rr];
#pragma unroll
      for (int off = 32; off; off >>= 1) a += __shfl_xor(a, off, 64);
      if (lane == 0) {
        int row = row0 + rr;                      // row = pos*256 + b
        sc[(row & 255) * 256 + (row >> 8)] = a;   // [b][pos]
      }
    }
    return;
  }
  if (blockIdx.x < 3072) {
    // ---- Gh[l] = h0[l] @ Whh[l]^T + bih + bhh
    __shared__ char smem[40960];
    const int j = blockIdx.x - 2048;
    const int l = j >> 8, inner = j & 255;
    const int cb = inner & 63, rb = inner >> 6;
    const int j0 = cb * 16, r0 = rb * 64;
    const float* A  = h0 + (size_t)l * 262144;
    const float* W  = (l == 0) ? Whh0 : (Whh_r + (size_t)(l - 1) * 4194304);
    const float* bi = (l == 0) ? bih0 : (bih_r + (size_t)(l - 1) * 4096);
    const float* bh = (l == 0) ? bhh0 : (bhh_r + (size_t)(l - 1) * 4096);
    f32x4 acc[2] = {};
    tile_gemm_ff<1024>(A, W, r0, j0, smem, acc);
    float* Go = Gh + (size_t)l * 1048576;
    const int rf = wave & 3, gg = wave >> 2;
    const int col = j0 + (lane & 15);
    const int rbase = r0 + rf * 16 + ((lane >> 4) << 2);
#pragma unroll
    for (int gi = 0; gi < 2; ++gi) {
      const int cg = (gg * 2 + gi) * 1024 + col;
#pragma unroll
      for (int q = 0; q < 4; ++q)
        Go[(size_t)(rbase + q) * 4096 + cg] = acc[gi][q] + bi[cg] + bh[cg];
    }
    return;
  }
  // ---- Wih fp32 -> bf16  (Wihb = [Wih0b (6291456) | Wih_rb (12582912)])
  const int tid = ((int)blockIdx.x - 3072) * 512 + t;    // 0..589823
#pragma unroll
  for (int n = 0; n < 8; ++n) {
    int idx = tid + n * 589824;                          // float4 index, 4718592 total
    float4 v = (idx < 1572864) ? ((const float4*)Wih0)[idx]
                               : ((const float4*)Wih_r)[idx - 1572864];
    bf16x4 o;
    o[0] = (__bf16)v.x; o[1] = (__bf16)v.y; o[2] = (__bf16)v.z; o[3] = (__bf16)v.w;
    ((bf16x4*)Wihb)[idx] = o;
  }
}

// ============ k_smx: softmax + applied_last + embedding -> xb ============
__global__ __launch_bounds__(256) void k_smx(const float* __restrict__ sc,
                                             const float* __restrict__ AO,
                                             const float* __restrict__ inp,
                                             const float* __restrict__ Wemb,
                                             const float* __restrict__ bemb,
                                             float* __restrict__ norm_out,
                                             __bf16* __restrict__ x) {
  __shared__ float red[4];
  __shared__ float wsm[32];
  const int b = blockIdx.x, t = threadIdx.x, lane = t & 63, wave = t >> 6;
  float s = sc[b * 256 + t];
  float m = s;
#pragma unroll
  for (int off = 32; off; off >>= 1) m = fmaxf(m, __shfl_xor(m, off, 64));
  if (lane == 0) red[wave] = m;
  __syncthreads();
  m = fmaxf(fmaxf(red[0], red[1]), fmaxf(red[2], red[3]));
  float e = __expf(s - m);
  float sum = e;
#pragma unroll
  for (int off = 32; off; off >>= 1) sum += __shfl_xor(sum, off, 64);
  __syncthreads();
  if (lane == 0) red[wave] = sum;
  __syncthreads();
  sum = red[0] + red[1] + red[2] + red[3];
  float nv = e / sum;
  norm_out[b * 256 + t] = nv;
  if (t >= 224) wsm[t - 224] = nv;
  __syncthreads();
  float acc[4] = {0.f, 0.f, 0.f, 0.f};
  const float* base = AO + ((size_t)224 * 256 + b) * 1024;
#pragma unroll 4
  for (int i = 0; i < 32; ++i) {
    float w = wsm[i];
    const float* rp = base + (size_t)i * 262144;
#pragma unroll
    for (int q = 0; q < 4; ++q) acc[q] += w * rp[t + 256 * q];
  }
#pragma unroll
  for (int q = 0; q < 4; ++q) x[(size_t)b * 1536 + t + 256 * q] = (__bf16)(8.0f * acc[q]);
  float i0 = inp[b * 2], i1 = inp[b * 2 + 1];
#pragma unroll
  for (int r = 0; r < 2; ++r) {
    int jj = t + 256 * r;
    float e2 = i0 * Wemb[jj * 2] + i1 * Wemb[jj * 2 + 1] + bemb[jj];
    x[(size_t)b * 1536 + 1024 + jj] = (__bf16)fmaxf(e2, 0.f);
  }
}

// ============ k_layer: GEMM (bf16 W) + Gh add + gates ============
template<int K>
__global__ __launch_bounds__(512) void k_layer(const __bf16* __restrict__ A,
                                               const __bf16* __restrict__ Wb,
                                               const float* __restrict__ Gh,
                                               const float* __restrict__ c0l,
                                               float* __restrict__ h_out,
                                               float* __restrict__ c_out,
                                               __bf16* __restrict__ hb) {
  __shared__ char smem[40960];
  float* exch = (float*)(smem + 32768);     // [4][2][256] floats = 8 KB
  const int t = threadIdx.x, lane = t & 63, wave = t >> 6;
  const int rf = wave & 3, gg = wave >> 2;
  const int cb = blockIdx.x & 63, rb = blockIdx.x >> 6;
  const int j0 = cb * 16, r0 = rb * 64;
  f32x4 acc[2] = {};
  tile_gemm_bb<K>(A, Wb, r0, j0, smem, acc);
  const int col = j0 + (lane & 15);
  const int rbase = r0 + rf * 16 + ((lane >> 4) << 2);
#pragma unroll
  for (int gi = 0; gi < 2; ++gi) {
    const float* gp = Gh + (size_t)rbase * 4096 + (gg * 2 + gi) * 1024 + col;
#pragma unroll
    for (int q = 0; q < 4; ++q) acc[gi][q] += gp[(size_t)q * 4096];
  }
  const int eidx = ((lane >> 4) << 2) * 16 + (lane & 15);
  __syncthreads();      // all MFMA reads of smem done before exch reuse
  if (gg == 1) {
#pragma unroll
    for (int gi = 0; gi < 2; ++gi)
#pragma unroll
      for (int q = 0; q < 4; ++q)
        exch[(rf * 2 + gi) * 256 + eidx + q * 16] = acc[gi][q];
  }
  __syncthreads();
  if (gg == 0) {
#pragma unroll
    for (int q = 0; q < 4; ++q) {
      const int row = rbase + q;
      float gv = exch[(rf * 2 + 0) * 256 + eidx + q * 16];
      float ov = exch[(rf * 2 + 1) * 256 + eidx + q * 16];
      float si = 1.f / (1.f + __expf(-acc[0][q]));
      float sf = 1.f / (1.f + __expf(-acc[1][q]));
      float so = 1.f / (1.f + __expf(-ov));
      float c2 = sf * c0l[(size_t)row * 1024 + col] + si * tanhf(gv);
      float h2 = so * tanhf(c2);
      h_out[(size_t)row * 1024 + col] = h2;
      c_out[(size_t)row * 1024 + col] = c2;
      hb[(size_t)row * 1024 + col] = (__bf16)h2;
    }
  }
}

// ============ k_final ============
__global__ __launch_bounds__(256) void k_final(const float* __restrict__ h3,
                                               const float* __restrict__ Wout,
                                               const float* __restrict__ bout,
                                               float* __restrict__ out) {
  const int lane = threadIdx.x & 63, wave = threadIdx.x >> 6;
  const int b = blockIdx.x * 4 + wave;
  const float4* hp = (const float4*)(h3 + (size_t)b * 1024);
  const float4* w0 = (const float4*)Wout;
  const float4* w1 = (const float4*)(Wout + 1024);
  float a0 = 0.f, a1 = 0.f;
#pragma unroll
  for (int q = 0; q < 4; ++q) {
    float4 hv = hp[lane + 64 * q];
    float4 v0 = w0[lane + 64 * q];
    float4 v1 = w1[lane + 64 * q];
    a0 += hv.x * v0.x + hv.y * v0.y + hv.z * v0.z + hv.w * v0.w;
    a1 += hv.x * v1.x + hv.y * v1.y + hv.z * v1.z + hv.w * v1.w;
  }
#pragma unroll
  for (int off = 32; off; off >>= 1) {
    a0 += __shfl_xor(a0, off, 64);
    a1 += __shfl_xor(a1, off, 64);
  }
  if (lane == 0) {
    out[b * 2]     = a0 + bout[0];
    out[b * 2 + 1] = a1 + bout[1];
  }
}

extern "C" void kernel_launch(void* const* d_in, const int* in_sizes, int n_in,
                              void* d_out, int out_size, void* d_ws, size_t ws_size,
                              hipStream_t stream) {
  const float* inp    = (const float*)d_in[0];
  const float* h0     = (const float*)d_in[1];
  const float* c0     = (const float*)d_in[2];
  const float* AO     = (const float*)d_in[3];
  const float* Wemb   = (const float*)d_in[4];
  const float* bemb   = (const float*)d_in[5];
  const float* Wattn  = (const float*)d_in[6];
  // d_in[7] = b_attn (cancels in softmax)
  const float* Wih0   = (const float*)d_in[8];
  const float* Whh0   = (const float*)d_in[9];
  const float* bih0   = (const float*)d_in[10];
  const float* bhh0   = (const float*)d_in[11];
  const float* Wih_r  = (const float*)d_in[12];
  const float* Whh_r  = (const float*)d_in[13];
  const float* bih_r  = (const float*)d_in[14];
  const float* bhh_r  = (const float*)d_in[15];
  const float* Wout   = (const float*)d_in[16];
  const float* bout   = (const float*)d_in[17];

  float* out = (float*)d_out;
  char* ws = (char*)d_ws;

  __bf16* Wihb  = (__bf16*)ws;                         // 36 MB bf16 [Wih0b|Wih_rb]
  float*  Gh    = (float*)(ws + 37748736);             // 16 MB [4][256][4096]
  __bf16* xb    = (__bf16*)(ws + 54525952);            // 768 KB [256][1536]
  __bf16* hb    = (__bf16*)(ws + 55312384);            // 2 MB [4][256][1024]
  float*  sc    = (float*)(ws + 57409536);             // 256 KB [256][256]
  __bf16* Wihb0 = Wihb;
  __bf16* Wihbr = Wihb + 6291456;

  k_front<<<4224, 512, 0, stream>>>(AO, Wattn, sc, h0, Whh0, Whh_r,
                                    bih0, bhh0, bih_r, bhh_r, Gh,
                                    Wih0, Wih_r, Wihb);
  k_smx<<<256, 256, 0, stream>>>(sc, AO, inp, Wemb, bemb, out + O_NORM, xb);

  k_layer<1536><<<256, 512, 0, stream>>>(xb, Wihb0, Gh, c0,
                                         out + O_H, out + O_C, hb);
  for (int l = 1; l < 4; ++l)
    k_layer<1024><<<256, 512, 0, stream>>>(hb + (size_t)(l - 1) * 262144,
                                           Wihbr + (size_t)(l - 1) * 4194304,
                                           Gh + (size_t)l * 1048576,
                                           c0 + (size_t)l * 262144,
                                           out + O_H + (size_t)l * 262144,
                                           out + O_C + (size_t)l * 262144,
                                           hb + (size_t)l * 262144);

  k_final<<<64, 256, 0, stream>>>(out + O_H + 3 * 262144, Wout, bout, out + O_FINAL);
}

// Round 11
// 153.210 us; speedup vs baseline: 2.3550x; 1.0055x over previous
//
#include <hip/hip_runtime.h>
#include <hip/hip_bf16.h>

typedef __bf16 bf16x8 __attribute__((ext_vector_type(8)));
typedef float  f32x4  __attribute__((ext_vector_type(4)));

// d_out offsets (floats)
#define O_FINAL 0
#define O_H     512
#define O_C     1049088      // 512 + 4*256*1024
#define O_NORM  2097664      // O_C + 4*256*1024

__device__ __forceinline__ bf16x8 cvt8(float4 a, float4 b) {
  bf16x8 r;
  r[0] = (__bf16)a.x; r[1] = (__bf16)a.y; r[2] = (__bf16)a.z; r[3] = (__bf16)a.w;
  r[4] = (__bf16)b.x; r[5] = (__bf16)b.y; r[6] = (__bf16)b.z; r[7] = (__bf16)b.w;
  return r;
}

// ============ staged tile GEMM cores (512 thr, 8 waves) ============
// Tile: 64 A-rows x [16 cols x 4 gates]. Wave w: rf=w&3 row-frag, gg=w>>2
// gate-pair. XOR-swizzled LDS rows (128B). Double-buffered LDS, ONE
// __syncthreads per K-step, 4-deep register prefetch.
// _bf: A bf16, W fp32 (cvt in staging)   _ff: A fp32, W fp32
template<int K>
__device__ __forceinline__ void tile_gemm_bf(const __bf16* __restrict__ A,
                                             const float* __restrict__ W,
                                             int r0, int j0, char* lds,
                                             f32x4 acc[2]) {
  constexpr int NK = K / 64;
  constexpr int D = 4;
  const int t = threadIdx.x, lane = t & 63, wave = t >> 6;
  const int rf = wave & 3, gg = wave >> 2;
  const int tr = t >> 3, chunk = t & 7;
  const float*  wsrc = W + (size_t)((tr >> 4) * 1024 + j0 + (tr & 15)) * K + chunk * 8;
  const __bf16* asrc = A + (size_t)(r0 + tr) * K + chunk * 8;
  const int sw_off = (chunk ^ (tr & 7)) << 4;
  const int woff = 8192 + tr * 128 + sw_off;
  const int aoff = tr * 128 + sw_off;
  const int a_tr  = rf * 16 + (lane & 15);
  const int w_tr0 = gg * 32 + (lane & 15);
  const int w_tr1 = w_tr0 + 16;
  const int ksel  = lane >> 4;

  float4 wp[D][2]; bf16x8 ap[D];
#pragma unroll
  for (int d = 0; d < D; ++d) {
    wp[d][0] = *(const float4*)(wsrc + d * 64);
    wp[d][1] = *(const float4*)(wsrc + d * 64 + 4);
    ap[d]    = *(const bf16x8*)(asrc + d * 64);
  }
#pragma unroll
  for (int s = 0; s < NK; ++s) {
    const int sl = s % D;
    char* buf = lds + (s & 1) * 16384;
    *(bf16x8*)(buf + aoff) = ap[sl];
    *(bf16x8*)(buf + woff) = cvt8(wp[sl][0], wp[sl][1]);
    if (s + D < NK) {
      wp[sl][0] = *(const float4*)(wsrc + (s + D) * 64);
      wp[sl][1] = *(const float4*)(wsrc + (s + D) * 64 + 4);
      ap[sl]    = *(const bf16x8*)(asrc + (s + D) * 64);
    }
    __syncthreads();
#pragma unroll
    for (int s2 = 0; s2 < 2; ++s2) {
      const int chk = s2 * 4 + ksel;
      bf16x8 af  = *(const bf16x8*)(buf + a_tr * 128 + ((chk ^ (a_tr & 7)) << 4));
      bf16x8 wf0 = *(const bf16x8*)(buf + 8192 + w_tr0 * 128 + ((chk ^ (w_tr0 & 7)) << 4));
      bf16x8 wf1 = *(const bf16x8*)(buf + 8192 + w_tr1 * 128 + ((chk ^ (w_tr1 & 7)) << 4));
      acc[0] = __builtin_amdgcn_mfma_f32_16x16x32_bf16(af, wf0, acc[0], 0, 0, 0);
      acc[1] = __builtin_amdgcn_mfma_f32_16x16x32_bf16(af, wf1, acc[1], 0, 0, 0);
    }
  }
}

template<int K>
__device__ __forceinline__ void tile_gemm_ff(const float* __restrict__ A,
                                             const float* __restrict__ W,
                                             int r0, int j0, char* lds,
                                             f32x4 acc[2]) {
  constexpr int NK = K / 64;
  constexpr int D = 4;
  const int t = threadIdx.x, lane = t & 63, wave = t >> 6;
  const int rf = wave & 3, gg = wave >> 2;
  const int tr = t >> 3, chunk = t & 7;
  const float* wsrc = W + (size_t)((tr >> 4) * 1024 + j0 + (tr & 15)) * K + chunk * 8;
  const float* asrc = A + (size_t)(r0 + tr) * K + chunk * 8;
  const int sw_off = (chunk ^ (tr & 7)) << 4;
  const int woff = 8192 + tr * 128 + sw_off;
  const int aoff = tr * 128 + sw_off;
  const int a_tr  = rf * 16 + (lane & 15);
  const int w_tr0 = gg * 32 + (lane & 15);
  const int w_tr1 = w_tr0 + 16;
  const int ksel  = lane >> 4;

  float4 wp[D][2], ap[D][2];
#pragma unroll
  for (int d = 0; d < D; ++d) {
    wp[d][0] = *(const float4*)(wsrc + d * 64);
    wp[d][1] = *(const float4*)(wsrc + d * 64 + 4);
    ap[d][0] = *(const float4*)(asrc + d * 64);
    ap[d][1] = *(const float4*)(asrc + d * 64 + 4);
  }
#pragma unroll
  for (int s = 0; s < NK; ++s) {
    const int sl = s % D;
    char* buf = lds + (s & 1) * 16384;
    *(bf16x8*)(buf + aoff) = cvt8(ap[sl][0], ap[sl][1]);
    *(bf16x8*)(buf + woff) = cvt8(wp[sl][0], wp[sl][1]);
    if (s + D < NK) {
      wp[sl][0] = *(const float4*)(wsrc + (s + D) * 64);
      wp[sl][1] = *(const float4*)(wsrc + (s + D) * 64 + 4);
      ap[sl][0] = *(const float4*)(asrc + (s + D) * 64);
      ap[sl][1] = *(const float4*)(asrc + (s + D) * 64 + 4);
    }
    __syncthreads();
#pragma unroll
    for (int s2 = 0; s2 < 2; ++s2) {
      const int chk = s2 * 4 + ksel;
      bf16x8 af  = *(const bf16x8*)(buf + a_tr * 128 + ((chk ^ (a_tr & 7)) << 4));
      bf16x8 wf0 = *(const bf16x8*)(buf + 8192 + w_tr0 * 128 + ((chk ^ (w_tr0 & 7)) << 4));
      bf16x8 wf1 = *(const bf16x8*)(buf + 8192 + w_tr1 * 128 + ((chk ^ (w_tr1 & 7)) << 4));
      acc[0] = __builtin_amdgcn_mfma_f32_16x16x32_bf16(af, wf0, acc[0], 0, 0, 0);
      acc[1] = __builtin_amdgcn_mfma_f32_16x16x32_bf16(af, wf1, acc[1], 0, 0, 0);
    }
  }
}

// ============ k_scores: sc[b*256+pos] = dot(AO[pos,b,:], w_y) ============
// (h_top@w_h + b_attn are per-b constants -> cancel in softmax)
__global__ __launch_bounds__(512) void k_scores(const float* __restrict__ AO,
                                                const float* __restrict__ Wattn,
                                                float* __restrict__ sc) {
  const int lane = threadIdx.x & 63, wave = threadIdx.x >> 6;
  const float* wy = Wattn + 1024;
  float4 wv[4];
#pragma unroll
  for (int q = 0; q < 4; ++q) wv[q] = *(const float4*)(wy + lane * 4 + 256 * q);
  const int row0 = (blockIdx.x * 8 + wave) * 4;
  float a4[4];
#pragma unroll
  for (int rr = 0; rr < 4; ++rr) {
    const float4* rp = (const float4*)(AO + (size_t)(row0 + rr) * 1024);
    float a = 0.f;
#pragma unroll
    for (int q = 0; q < 4; ++q) {
      float4 v = rp[lane + 64 * q];
      a += v.x * wv[q].x + v.y * wv[q].y + v.z * wv[q].z + v.w * wv[q].w;
    }
    a4[rr] = a;
  }
#pragma unroll
  for (int rr = 0; rr < 4; ++rr) {
    float a = a4[rr];
#pragma unroll
    for (int off = 32; off; off >>= 1) a += __shfl_xor(a, off, 64);
    if (lane == 0) {
      int row = row0 + rr;                      // row = pos*256 + b
      sc[(row & 255) * 256 + (row >> 8)] = a;   // [b][pos]
    }
  }
}

// ============ k_smx: softmax + applied_last + embedding -> xb ============
__global__ __launch_bounds__(256) void k_smx(const float* __restrict__ sc,
                                             const float* __restrict__ AO,
                                             const float* __restrict__ inp,
                                             const float* __restrict__ Wemb,
                                             const float* __restrict__ bemb,
                                             float* __restrict__ norm_out,
                                             __bf16* __restrict__ x) {
  __shared__ float red[4];
  __shared__ float wsm[32];
  const int b = blockIdx.x, t = threadIdx.x, lane = t & 63, wave = t >> 6;
  float s = sc[b * 256 + t];
  float m = s;
#pragma unroll
  for (int off = 32; off; off >>= 1) m = fmaxf(m, __shfl_xor(m, off, 64));
  if (lane == 0) red[wave] = m;
  __syncthreads();
  m = fmaxf(fmaxf(red[0], red[1]), fmaxf(red[2], red[3]));
  float e = __expf(s - m);
  float sum = e;
#pragma unroll
  for (int off = 32; off; off >>= 1) sum += __shfl_xor(sum, off, 64);
  __syncthreads();
  if (lane == 0) red[wave] = sum;
  __syncthreads();
  sum = red[0] + red[1] + red[2] + red[3];
  float nv = e / sum;
  norm_out[b * 256 + t] = nv;
  if (t >= 224) wsm[t - 224] = nv;
  __syncthreads();
  float acc[4] = {0.f, 0.f, 0.f, 0.f};
  const float* base = AO + ((size_t)224 * 256 + b) * 1024;
#pragma unroll 4
  for (int i = 0; i < 32; ++i) {
    float w = wsm[i];
    const float* rp = base + (size_t)i * 262144;
#pragma unroll
    for (int q = 0; q < 4; ++q) acc[q] += w * rp[t + 256 * q];
  }
#pragma unroll
  for (int q = 0; q < 4; ++q) x[(size_t)b * 1536 + t + 256 * q] = (__bf16)(8.0f * acc[q]);
  float i0 = inp[b * 2], i1 = inp[b * 2 + 1];
#pragma unroll
  for (int r = 0; r < 2; ++r) {
    int jj = t + 256 * r;
    float e2 = i0 * Wemb[jj * 2] + i1 * Wemb[jj * 2 + 1] + bemb[jj];
    x[(size_t)b * 1536 + 1024 + jj] = (__bf16)fmaxf(e2, 0.f);
  }
}

// ============ k_layer: acc = A@Wih^T + h0@Whh^T; +biases; gates ============
template<int KA>
__global__ __launch_bounds__(512) void k_layer(const __bf16* __restrict__ A,
                                               const float* __restrict__ Wih,
                                               const float* __restrict__ h0l,
                                               const float* __restrict__ Whh,
                                               const float* __restrict__ bi,
                                               const float* __restrict__ bh,
                                               const float* __restrict__ c0l,
                                               float* __restrict__ h_out,
                                               float* __restrict__ c_out,
                                               __bf16* __restrict__ hb) {
  __shared__ char smem[40960];
  float* exch = (float*)(smem + 32768);     // [4*2][256] floats = 8 KB
  const int t = threadIdx.x, lane = t & 63, wave = t >> 6;
  const int rf = wave & 3, gg = wave >> 2;
  const int cb = blockIdx.x & 63, rb = blockIdx.x >> 6;
  const int j0 = cb * 16, r0 = rb * 64;
  f32x4 acc[2] = {};
  tile_gemm_bf<KA>(A, Wih, r0, j0, smem, acc);
  tile_gemm_ff<1024>(h0l, Whh, r0, j0, smem, acc);
  const int col = j0 + (lane & 15);
  const int rbase = r0 + rf * 16 + ((lane >> 4) << 2);
  const int eidx = ((lane >> 4) << 2) * 16 + (lane & 15);
  // add biases for this wave's two gates
#pragma unroll
  for (int gi = 0; gi < 2; ++gi) {
    const int cg = (gg * 2 + gi) * 1024 + col;
    const float bsum = bi[cg] + bh[cg];
    acc[gi][0] += bsum; acc[gi][1] += bsum; acc[gi][2] += bsum; acc[gi][3] += bsum;
  }
  if (gg == 1) {
#pragma unroll
    for (int gi = 0; gi < 2; ++gi)
#pragma unroll
      for (int q = 0; q < 4; ++q)
        exch[(rf * 2 + gi) * 256 + eidx + q * 16] = acc[gi][q];
  }
  __syncthreads();
  if (gg == 0) {
#pragma unroll
    for (int q = 0; q < 4; ++q) {
      const int row = rbase + q;
      float gv = exch[(rf * 2 + 0) * 256 + eidx + q * 16];
      float ov = exch[(rf * 2 + 1) * 256 + eidx + q * 16];
      float si = 1.f / (1.f + __expf(-acc[0][q]));
      float sf = 1.f / (1.f + __expf(-acc[1][q]));
      float so = 1.f / (1.f + __expf(-ov));
      float c2 = sf * c0l[(size_t)row * 1024 + col] + si * tanhf(gv);
      float h2 = so * tanhf(c2);
      h_out[(size_t)row * 1024 + col] = h2;
      c_out[(size_t)row * 1024 + col] = c2;
      hb[(size_t)row * 1024 + col] = (__bf16)h2;
    }
  }
}

// ============ k_final ============
__global__ __launch_bounds__(256) void k_final(const float* __restrict__ h3,
                                               const float* __restrict__ Wout,
                                               const float* __restrict__ bout,
                                               float* __restrict__ out) {
  const int lane = threadIdx.x & 63, wave = threadIdx.x >> 6;
  const int b = blockIdx.x * 4 + wave;
  const float4* hp = (const float4*)(h3 + (size_t)b * 1024);
  const float4* w0 = (const float4*)Wout;
  const float4* w1 = (const float4*)(Wout + 1024);
  float a0 = 0.f, a1 = 0.f;
#pragma unroll
  for (int q = 0; q < 4; ++q) {
    float4 hv = hp[lane + 64 * q];
    float4 v0 = w0[lane + 64 * q];
    float4 v1 = w1[lane + 64 * q];
    a0 += hv.x * v0.x + hv.y * v0.y + hv.z * v0.z + hv.w * v0.w;
    a1 += hv.x * v1.x + hv.y * v1.y + hv.z * v1.z + hv.w * v1.w;
  }
#pragma unroll
  for (int off = 32; off; off >>= 1) {
    a0 += __shfl_xor(a0, off, 64);
    a1 += __shfl_xor(a1, off, 64);
  }
  if (lane == 0) {
    out[b * 2]     = a0 + bout[0];
    out[b * 2 + 1] = a1 + bout[1];
  }
}

extern "C" void kernel_launch(void* const* d_in, const int* in_sizes, int n_in,
                              void* d_out, int out_size, void* d_ws, size_t ws_size,
                              hipStream_t stream) {
  const float* inp    = (const float*)d_in[0];
  const float* h0     = (const float*)d_in[1];
  const float* c0     = (const float*)d_in[2];
  const float* AO     = (const float*)d_in[3];
  const float* Wemb   = (const float*)d_in[4];
  const float* bemb   = (const float*)d_in[5];
  const float* Wattn  = (const float*)d_in[6];
  // d_in[7] = b_attn (cancels in softmax)
  const float* Wih0   = (const float*)d_in[8];
  const float* Whh0   = (const float*)d_in[9];
  const float* bih0   = (const float*)d_in[10];
  const float* bhh0   = (const float*)d_in[11];
  const float* Wih_r  = (const float*)d_in[12];
  const float* Whh_r  = (const float*)d_in[13];
  const float* bih_r  = (const float*)d_in[14];
  const float* bhh_r  = (const float*)d_in[15];
  const float* Wout   = (const float*)d_in[16];
  const float* bout   = (const float*)d_in[17];

  float* out = (float*)d_out;
  char* ws = (char*)d_ws;

  float*  sc = (float*)ws;                    // 256 KB [256][256]
  __bf16* xb = (__bf16*)(ws + 262144);        // 768 KB [256][1536]
  __bf16* hb = (__bf16*)(ws + 1048576);       // 2 MB [4][256][1024]

  k_scores<<<2048, 512, 0, stream>>>(AO, Wattn, sc);
  k_smx<<<256, 256, 0, stream>>>(sc, AO, inp, Wemb, bemb, out + O_NORM, xb);

  k_layer<1536><<<256, 512, 0, stream>>>(xb, Wih0, h0, Whh0, bih0, bhh0, c0,
                                         out + O_H, out + O_C, hb);
  for (int l = 1; l < 4; ++l)
    k_layer<1024><<<256, 512, 0, stream>>>(hb + (size_t)(l - 1) * 262144,
                                           Wih_r + (size_t)(l - 1) * 4194304,
                                           h0 + (size_t)l * 262144,
                                           Whh_r + (size_t)(l - 1) * 4194304,
                                           bih_r + (size_t)(l - 1) * 4096,
                                           bhh_r + (size_t)(l - 1) * 4096,
                                           c0 + (size_t)l * 262144,
                                           out + O_H + (size_t)l * 262144,
                                           out + O_C + (size_t)l * 262144,
                                           hb + (size_t)l * 262144);

  k_final<<<64, 256, 0, stream>>>(out + O_H + 3 * 262144, Wout, bout, out + O_FINAL);
}